// Round 10
// baseline (33.644 us; speedup 1.0000x reference)
//
#include <hip/hip_runtime.h>
#include <hip/hip_fp16.h>

#define OUTF 11008
#define INF  4096

typedef unsigned int uint;
typedef __attribute__((ext_vector_type(8))) _Float16 f16x8;  // MFMA A/B (4 VGPR)
typedef __attribute__((ext_vector_type(4))) float f32x4;     // MFMA C/D

typedef __attribute__((address_space(1))) void gvoid_t;
typedef __attribute__((address_space(3))) void svoid_t;

union UA { uint4 u4; uint u[4]; f16x8 v; };
union UH { uint u; __half2 h; };
union USH { unsigned short s; __half h; };

#define WAITV(n) asm volatile("s_waitcnt vmcnt(" #n ")" ::: "memory")
#define FENCE()  asm volatile("" ::: "memory")   // compiler-order pin

// Single kernel. Block = 256 thr = 4 waves; one 16-row o-tile; wave wv owns
// K-quarter wv. Barrier-free pipelines; one LDS reduction at the end.
__global__ __launch_bounds__(256, 3) void lin2bit_kernel(
    const float* __restrict__ x, const int* __restrict__ wq,
    const float* __restrict__ wn, const float* __restrict__ bias,
    float* __restrict__ out)
{
  // [0,2048) LUT | [2048,10240) norms: wv*2048 | [10240,43008) W slabs: wv*8192
  __shared__ __align__(16) char lds[43008];
  char* LUT = lds;

  const int tid = threadIdx.x;
  const int wv  = tid >> 6;
  const int l   = tid & 63;
  const int col = l & 15;            // A-row (m) / B-col (o)
  const int q   = l >> 4;            // lane covers k = 8q..8q+7 of each group
  const int o0  = (int)blockIdx.x << 4;

  char* NL = lds + 2048 + wv * 2048;         // norms: [r][128B], granule-swizzled
  char* W0 = lds + 10240 + wv * 8192;        // chunk slab A: [r][256B], swizzled
  char* W1 = W0 + 4096;                      // chunk slab B

  const char* wqb = (const char*)wq;
  const char* wnb = (const char*)wn;

  // ---- norms DMA: 2 instr, 8 rows each, 16B/lane, source-side XOR swizzle
  {
    const int r7 = l >> 3;
    const char* s0 = wnb + (size_t)(o0 + r7) * 512 + wv * 128 + (((l & 7) ^ r7) << 4);
#pragma unroll
    for (int i = 0; i < 2; ++i)
      __builtin_amdgcn_global_load_lds((gvoid_t*)(s0 + (size_t)i * 8 * 512),
                                       (svoid_t*)(NL + i * 1024 + l * 16), 16, 0, 0);
  }
  FENCE();

  // chunk = 8 K-groups = 16 rows x 256B. DMA: 4 instr, 4 rows each.
#define STAGE_W(c, buf) { \
    _Pragma("unroll") \
    for (int i = 0; i < 4; ++i) { \
      const int r = 4 * i + (l >> 4); \
      const char* src = wqb + (size_t)(o0 + r) * 4096 + wv * 1024 + (c) * 256 \
                        + (((l & 15) ^ (r & 7)) << 4); \
      __builtin_amdgcn_global_load_lds((gvoid_t*)src, \
                                       (svoid_t*)((buf) + i * 1024 + l * 16), 16, 0, 0); \
    } }

  // ---- x fragment staging, direct from f32 x (L2-hot): 16 float4 per chunk
  const float* xrow = x + (size_t)col * INF + wv * 1024 + q * 8;
  float4 xs[16];
#define LOAD_X(c) { \
    _Pragma("unroll") \
    for (int j = 0; j < 8; ++j) { \
      xs[2 * j]     = *(const float4*)(xrow + ((c) * 8 + j) * 32); \
      xs[2 * j + 1] = *(const float4*)(xrow + ((c) * 8 + j) * 32 + 4); \
    } }

  STAGE_W(0, W0);  FENCE();
  LOAD_X(0);       FENCE();
  STAGE_W(1, W1);  FENCE();
  // outstanding: 2 + 4 + 16 + 4 = 26

  // ---- LUT build on VALU while 26 VMEM in flight (duplicate identical writes
  // by all 4 waves -> benign, no barrier needed)
  {
    USH h0, h1, h2, h3;
    h0.h = __float2half(-1.0f);  h1.h = __float2half(-0.333f);
    h2.h = __float2half(0.333f); h3.h = __float2half(1.0f);
    const uint hv[4] = {h0.s, h1.s, h2.s, h3.s};
#pragma unroll
    for (int e = 0; e < 4; ++e) {
      const int idx = e * 64 + l;
      const uint lo = hv[idx & 3]        | (hv[(idx >> 2) & 3] << 16);
      const uint hi = hv[(idx >> 4) & 3] | (hv[(idx >> 6) & 3] << 16);
      *(uint2*)(LUT + idx * 8) = make_uint2(lo, hi);
    }
  }

  f32x4 acc = {0.f, 0.f, 0.f, 0.f};
  const int cs7 = col & 7;
  const int qh  = q >> 1;
  const int ql8 = (q & 1) * 8;
  UA af[8];

  // cvt staged f32 -> f16 fragments (xs regs freed for next chunk's issue)
#define CVT_AF() { \
    _Pragma("unroll") \
    for (int j = 0; j < 8; ++j) { \
      UH c0, c1, c2, c3; \
      c0.h = __floats2half2_rn(xs[2*j].x,   xs[2*j].y); \
      c1.h = __floats2half2_rn(xs[2*j].z,   xs[2*j].w); \
      c2.h = __floats2half2_rn(xs[2*j+1].x, xs[2*j+1].y); \
      c3.h = __floats2half2_rn(xs[2*j+1].z, xs[2*j+1].w); \
      af[j].u[0] = c0.u; af[j].u[1] = c1.u; af[j].u[2] = c2.u; af[j].u[3] = c3.u; \
    } }

#define CHUNK(wb, c) { \
    const float4 n0 = *(const float4*)(NL + col * 128 + (((2 * (c))     ^ cs7) << 4)); \
    const float4 n1 = *(const float4*)(NL + col * 128 + (((2 * (c) + 1) ^ cs7) << 4)); \
    __half2 nv2[8]; \
    nv2[0] = __floats2half2_rn(n0.x, n0.x); nv2[1] = __floats2half2_rn(n0.y, n0.y); \
    nv2[2] = __floats2half2_rn(n0.z, n0.z); nv2[3] = __floats2half2_rn(n0.w, n0.w); \
    nv2[4] = __floats2half2_rn(n1.x, n1.x); nv2[5] = __floats2half2_rn(n1.y, n1.y); \
    nv2[6] = __floats2half2_rn(n1.z, n1.z); nv2[7] = __floats2half2_rn(n1.w, n1.w); \
    _Pragma("unroll") \
    for (int j = 0; j < 8; ++j) { \
      const uint2 p  = *(const uint2*)((wb) + col * 256 + (((2 * j + qh) ^ cs7) << 4) + ql8); \
      const uint2 e0 = *(const uint2*)(LUT + ((size_t)(uint)p.x << 3)); \
      const uint2 e1 = *(const uint2*)(LUT + ((size_t)(uint)p.y << 3)); \
      UH a0, a1, a2, a3, b0, b1, b2, b3; \
      a0.u = e0.x; a1.u = e0.y; a2.u = e1.x; a3.u = e1.y; \
      b0.h = __hmul2(a0.h, nv2[j]); b1.h = __hmul2(a1.h, nv2[j]); \
      b2.h = __hmul2(a2.h, nv2[j]); b3.h = __hmul2(a3.h, nv2[j]); \
      UA B; B.u[0] = b0.u; B.u[1] = b1.u; B.u[2] = b2.u; B.u[3] = b3.u; \
      acc = __builtin_amdgcn_mfma_f32_16x16x32_f16(af[j].v, B.v, acc, 0, 0, 0); \
    } }

  // ladder (counts: norms 2 | W 4 | X 16):
  WAITV(4);  CVT_AF();  FENCE(); LOAD_X(1); FENCE();   // X0 done; W1 in flight
  CHUNK(W0, 0)
  FENCE();   STAGE_W(2, W0);  FENCE();
  WAITV(4);  CVT_AF();  FENCE(); LOAD_X(2); FENCE();   // W1+X1 done; W2 in flight
  CHUNK(W1, 1)
  FENCE();   STAGE_W(3, W1);  FENCE();
  WAITV(4);  CVT_AF();  FENCE(); LOAD_X(3); FENCE();   // W2+X2 done; W3 in flight
  CHUNK(W0, 2)
  WAITV(0);  CVT_AF();                                  // W3+X3 done
  CHUNK(W1, 3)
#undef CHUNK
#undef CVT_AF
#undef LOAD_X
#undef STAGE_W

  // ---- cross-wave K reduction (overlay on LUT region) + bias + store
  __syncthreads();
  float* red = (float*)lds;          // 1024 floats = 4 KB
  red[wv * 256 +   0 + l] = acc[0];
  red[wv * 256 +  64 + l] = acc[1];
  red[wv * 256 + 128 + l] = acc[2];
  red[wv * 256 + 192 + l] = acc[3];
  __syncthreads();
  const int t = tid;
  const float s = red[t] + red[256 + t] + red[512 + t] + red[768 + t];
  const int m  = ((t & 63) >> 4) * 4 + (t >> 6);   // D row = q*4 + reg
  const int oc = t & 15;                            // D col
  out[(size_t)m * OUTF + o0 + oc] = s + bias[o0 + oc];
}

extern "C" void kernel_launch(void* const* d_in, const int* in_sizes, int n_in,
                              void* d_out, int out_size, void* d_ws, size_t ws_size,
                              hipStream_t stream) {
  (void)in_sizes; (void)n_in; (void)out_size; (void)d_ws; (void)ws_size;
  const float* x    = (const float*)d_in[0];
  const int*   wq   = (const int*)d_in[1];
  const float* wn   = (const float*)d_in[2];
  const float* bias = (const float*)d_in[3];
  float*       out  = (float*)d_out;
  lin2bit_kernel<<<dim3(OUTF / 16), dim3(256), 0, stream>>>(x, wq, wn, bias, out);
}

// Round 11
// 23.221 us; speedup vs baseline: 1.4489x; 1.4489x over previous
//
#include <hip/hip_runtime.h>
#include <hip/hip_fp16.h>

#define OUTF 11008
#define INF  4096

typedef unsigned int uint;
typedef unsigned long long ull;
typedef __attribute__((ext_vector_type(8))) _Float16 f16x8;  // MFMA A/B (4 VGPR)
typedef __attribute__((ext_vector_type(4))) float f32x4;     // MFMA C/D

typedef __attribute__((address_space(1))) void gvoid_t;
typedef __attribute__((address_space(3))) void svoid_t;

union UA { uint4 u4; uint u[4]; f16x8 v; };
union UH { uint u; __half2 h; };

#define WAITV(n) asm volatile("s_waitcnt vmcnt(" #n ")" ::: "memory")
#define FENCE()  asm volatile("" ::: "memory")   // compiler-order pin

// ---- pre-pack x (f32 16x4096) -> f16 MFMA A-fragments.
// xpk[kblk*64+l] : lane l (col=l&15,q=l>>4) holds x[col][kblk*32+q*8 .. +8] as 8 f16
__global__ __launch_bounds__(256) void pack_x_kernel(const float* __restrict__ x,
                                                     uint4* __restrict__ xpk) {
  const int t = (int)blockIdx.x * 256 + (int)threadIdx.x;   // 0..8191
  const int kblk = t >> 6, l = t & 63, col = l & 15, q = l >> 4;
  const float* src = x + (size_t)col * INF + kblk * 32 + q * 8;
  const float4 a = *(const float4*)src;
  const float4 b = *(const float4*)(src + 4);
  UH c0, c1, c2, c3;
  c0.h = __floats2half2_rn(a.x, a.y);
  c1.h = __floats2half2_rn(a.z, a.w);
  c2.h = __floats2half2_rn(b.x, b.y);
  c3.h = __floats2half2_rn(b.z, b.w);
  xpk[t] = make_uint4(c0.u, c1.u, c2.u, c3.u);
}

// Block = 256 thr = 4 waves; one 16-row o-tile; wave wv owns K-quarter wv.
// Barrier-free pipelines; single LDS reduction at the end. Pure-VALU dequant.
__global__ __launch_bounds__(256, 4) void lin2bit_kernel(
    const uint4* __restrict__ xpk, const int* __restrict__ wq,
    const float* __restrict__ wn, const float* __restrict__ bias,
    float* __restrict__ out)
{
  // [0,8192) norms: wv*2048 | [8192,40960) W slabs: wv*8192  (total 40 KB -> 4 blk/CU)
  __shared__ __align__(16) char lds[40960];

  const int tid = threadIdx.x;
  const int wv  = tid >> 6;
  const int l   = tid & 63;
  const int col = l & 15;            // A-row (m) / B-col (o)
  const int q   = l >> 4;            // lane covers k = 8q..8q+7 of each group
  const int o0  = (int)blockIdx.x << 4;

  char* NL = lds + wv * 2048;                // norms: [r][128B], granule-swizzled
  char* W0 = lds + 8192 + wv * 8192;         // chunk slab A: [r][256B], swizzled
  char* W1 = W0 + 4096;                      // chunk slab B

  const char* wqb = (const char*)wq;
  const char* wnb = (const char*)wn;

  // ---- norms DMA: 2 instr, 8 rows each, 16B/lane, source-side XOR swizzle
  {
    const int r7 = l >> 3;
    const char* s0 = wnb + (size_t)(o0 + r7) * 512 + wv * 128 + (((l & 7) ^ r7) << 4);
#pragma unroll
    for (int i = 0; i < 2; ++i)
      __builtin_amdgcn_global_load_lds((gvoid_t*)(s0 + (size_t)i * 8 * 512),
                                       (svoid_t*)(NL + i * 1024 + l * 16), 16, 0, 0);
  }
  FENCE();

  // chunk = 8 K-groups = 16 rows x 256B. DMA: 4 instr, 4 rows each.
#define STAGE_W(c, buf) { \
    _Pragma("unroll") \
    for (int i = 0; i < 4; ++i) { \
      const int r = 4 * i + (l >> 4); \
      const char* src = wqb + (size_t)(o0 + r) * 4096 + wv * 1024 + (c) * 256 \
                        + (((l & 15) ^ (r & 7)) << 4); \
      __builtin_amdgcn_global_load_lds((gvoid_t*)src, \
                                       (svoid_t*)((buf) + i * 1024 + l * 16), 16, 0, 0); \
    } }

#define LOAD_AF(buf, c) { \
    _Pragma("unroll") \
    for (int j = 0; j < 8; ++j) \
      (buf)[j].u4 = xpk[(size_t)(wv * 32 + (c) * 8 + j) * 64 + l]; }

  UA afA[8], afB[8];
  STAGE_W(0, W0);  FENCE();
  LOAD_AF(afA, 0); FENCE();
  STAGE_W(1, W1);  FENCE();
  LOAD_AF(afB, 1); FENCE();
  // outstanding: 2 + 4 + 8 + 4 + 8 = 26

  f32x4 acc = {0.f, 0.f, 0.f, 0.f};
  const int cs7 = col & 7;
  const int qh  = q >> 1;
  const int ql8 = (q & 1) * 8;

  // Pure-VALU dequant (proven in R4/R5): 64-bit f16 table per group, shift-extract.
#define CHUNK(wb, af, c) { \
    const float4 n0 = *(const float4*)(NL + col * 128 + (((2 * (c))     ^ cs7) << 4)); \
    const float4 n1 = *(const float4*)(NL + col * 128 + (((2 * (c) + 1) ^ cs7) << 4)); \
    const float n8[8] = {n0.x, n0.y, n0.z, n0.w, n1.x, n1.y, n1.z, n1.w}; \
    _Pragma("unroll") \
    for (int j = 0; j < 8; ++j) { \
      const uint2 p  = *(const uint2*)((wb) + col * 256 + (((2 * j + qh) ^ cs7) << 4) + ql8); \
      const float nv  = n8[j]; \
      const float nv3 = nv * 0.333f; \
      UH tlo, thi; \
      tlo.h = __floats2half2_rn(-nv, -nv3); \
      thi.h = __floats2half2_rn(nv3, nv); \
      const ull T = ((ull)thi.u << 32) | (ull)tlo.u; \
      const uint p0 = p.x << 4, p1 = p.y << 4; \
      const uint w0 = (uint)(T >> (p0 & 0x30u)); \
      const uint w1 = (uint)(T >> ((p0 >> 2) & 0x30u)); \
      const uint w2 = (uint)(T >> ((p0 >> 4) & 0x30u)); \
      const uint w3 = (uint)(T >> ((p0 >> 6) & 0x30u)); \
      const uint w4 = (uint)(T >> (p1 & 0x30u)); \
      const uint w5 = (uint)(T >> ((p1 >> 2) & 0x30u)); \
      const uint w6 = (uint)(T >> ((p1 >> 4) & 0x30u)); \
      const uint w7 = (uint)(T >> ((p1 >> 6) & 0x30u)); \
      UA B; \
      B.u[0] = (w0 & 0xFFFFu) | (w1 << 16); \
      B.u[1] = (w2 & 0xFFFFu) | (w3 << 16); \
      B.u[2] = (w4 & 0xFFFFu) | (w5 << 16); \
      B.u[3] = (w6 & 0xFFFFu) | (w7 << 16); \
      acc = __builtin_amdgcn_mfma_f32_16x16x32_f16((af)[j].v, B.v, acc, 0, 0, 0); \
    } }

  // ladder: every wait targets loads issued a full chunk earlier
  WAITV(12); CHUNK(W0, afA, 0)
  FENCE();   STAGE_W(2, W0);  FENCE();  LOAD_AF(afA, 2);  FENCE();
  WAITV(12); CHUNK(W1, afB, 1)
  FENCE();   STAGE_W(3, W1);  FENCE();  LOAD_AF(afB, 3);  FENCE();
  WAITV(12); CHUNK(W0, afA, 2)
  WAITV(0);  CHUNK(W1, afB, 3)
#undef CHUNK
#undef STAGE_W
#undef LOAD_AF

  // ---- cross-wave K reduction (overlay on norms region) + bias + store
  __syncthreads();
  float* red = (float*)lds;          // 1024 floats = 4 KB
  red[wv * 256 +   0 + l] = acc[0];
  red[wv * 256 +  64 + l] = acc[1];
  red[wv * 256 + 128 + l] = acc[2];
  red[wv * 256 + 192 + l] = acc[3];
  __syncthreads();
  const int t = tid;
  const float s = red[t] + red[256 + t] + red[512 + t] + red[768 + t];
  const int m  = ((t & 63) >> 4) * 4 + (t >> 6);   // D row = q*4 + reg
  const int oc = t & 15;                            // D col
  out[(size_t)m * OUTF + o0 + oc] = s + bias[o0 + oc];
}

extern "C" void kernel_launch(void* const* d_in, const int* in_sizes, int n_in,
                              void* d_out, int out_size, void* d_ws, size_t ws_size,
                              hipStream_t stream) {
  (void)in_sizes; (void)n_in; (void)out_size; (void)ws_size;
  const float* x    = (const float*)d_in[0];
  const int*   wq   = (const int*)d_in[1];
  const float* wn   = (const float*)d_in[2];
  const float* bias = (const float*)d_in[3];
  float*       out  = (float*)d_out;
  uint4*       xpk  = (uint4*)d_ws;   // 128 KB workspace
  pack_x_kernel<<<dim3(32), dim3(256), 0, stream>>>(x, xpk);
  lin2bit_kernel<<<dim3(OUTF / 16), dim3(256), 0, stream>>>(xpk, wq, wn, bias, out);
}

// Round 12
// 22.515 us; speedup vs baseline: 1.4943x; 1.0314x over previous
//
#include <hip/hip_runtime.h>
#include <hip/hip_fp16.h>

#define OUTF 11008
#define INF  4096

typedef unsigned int uint;
typedef __attribute__((ext_vector_type(8))) _Float16 f16x8;  // MFMA A/B (4 VGPR)
typedef __attribute__((ext_vector_type(4))) float f32x4;     // MFMA C/D

typedef __attribute__((address_space(1))) void gvoid_t;
typedef __attribute__((address_space(3))) void svoid_t;

union UA { uint4 u4; uint u[4]; f16x8 v; };
union UH { uint u; __half2 h; };
union USH { unsigned short s; __half h; };

#define WAITV(n) asm volatile("s_waitcnt vmcnt(" #n ")" ::: "memory")
#define FENCE()  asm volatile("" ::: "memory")   // compiler-order pin

// ---- pre-pack x (f32 16x4096) -> f16 MFMA A-fragments.
// xpk[kblk*64+l] : lane l (col=l&15,q=l>>4) holds x[col][kblk*32+q*8 .. +8] as 8 f16
__global__ __launch_bounds__(256) void pack_x_kernel(const float* __restrict__ x,
                                                     uint4* __restrict__ xpk) {
  const int t = (int)blockIdx.x * 256 + (int)threadIdx.x;   // 0..8191
  const int kblk = t >> 6, l = t & 63, col = l & 15, q = l >> 4;
  const float* src = x + (size_t)col * INF + kblk * 32 + q * 8;
  const float4 a = *(const float4*)src;
  const float4 b = *(const float4*)(src + 4);
  UH c0, c1, c2, c3;
  c0.h = __floats2half2_rn(a.x, a.y);
  c1.h = __floats2half2_rn(a.z, a.w);
  c2.h = __floats2half2_rn(b.x, b.y);
  c3.h = __floats2half2_rn(b.z, b.w);
  xpk[t] = make_uint4(c0.u, c1.u, c2.u, c3.u);
}

// Block = 256 thr = 4 waves; one 16-row o-tile; wave wv owns K-quarter wv
// (32 groups = 4 chunks of 8). Triple-buffered W slabs, 2.5-chunk prefetch.
__global__ __launch_bounds__(256, 3) void lin2bit_kernel(
    const uint4* __restrict__ xpk, const int* __restrict__ wq,
    const float* __restrict__ wn, const float* __restrict__ bias,
    float* __restrict__ out)
{
  // [0,2048) LUT | [2048,51200) W: wave wv at 2048+wv*12288, 3 x 4KB buffers
  __shared__ __align__(16) char lds[51200];
  char* LUT = lds;

  const int tid = threadIdx.x;
  const int wv  = tid >> 6;
  const int l   = tid & 63;
  const int col = l & 15;
  const int q   = l >> 4;
  const int o0  = (int)blockIdx.x << 4;

  char* WB0 = lds + 2048 + wv * 12288;
  char* WB1 = WB0 + 4096;
  char* WB2 = WB0 + 8192;

  const char* wqb = (const char*)wq;

#define STAGE_W(c, buf) { \
    _Pragma("unroll") \
    for (int i = 0; i < 4; ++i) { \
      const int r = 4 * i + (l >> 4); \
      const char* src = wqb + (size_t)(o0 + r) * 4096 + wv * 1024 + (c) * 256 \
                        + (((l & 15) ^ (r & 7)) << 4); \
      __builtin_amdgcn_global_load_lds((gvoid_t*)src, \
                                       (svoid_t*)((buf) + i * 1024 + l * 16), 16, 0, 0); \
    } }

#define LOAD_AF(buf, c) { \
    _Pragma("unroll") \
    for (int j = 0; j < 8; ++j) \
      (buf)[j].u4 = xpk[(size_t)(wv * 32 + (c) * 8 + j) * 64 + l]; }

  // ---- issue: NR(8) | W0(4) AF0(8) | W1(4) AF1(8) | W2(4) AF2(8) = 44 outstanding
  float4 nf[8];
  {
    const float4* nptr = (const float4*)(wn + (size_t)(o0 + col) * 128 + wv * 32);
#pragma unroll
    for (int i = 0; i < 8; ++i) nf[i] = nptr[i];
  }
  FENCE();
  UA afA[8], afB[8], afC[8];
  STAGE_W(0, WB0);  FENCE();
  LOAD_AF(afA, 0);  FENCE();
  STAGE_W(1, WB1);  FENCE();
  LOAD_AF(afB, 1);  FENCE();
  STAGE_W(2, WB2);  FENCE();
  LOAD_AF(afC, 2);  FENCE();

  // ---- LUT build on VALU while 44 VMEM in flight
  {
    USH h0, h1, h2, h3;
    h0.h = __float2half(-1.0f);  h1.h = __float2half(-0.333f);
    h2.h = __float2half(0.333f); h3.h = __float2half(1.0f);
    const uint hv[4] = {h0.s, h1.s, h2.s, h3.s};
#pragma unroll
    for (int e = 0; e < 4; ++e) {
      const int idx = e * 64 + l;
      const uint lo = hv[idx & 3]        | (hv[(idx >> 2) & 3] << 16);
      const uint hi = hv[(idx >> 4) & 3] | (hv[(idx >> 6) & 3] << 16);
      *(uint2*)(LUT + idx * 8) = make_uint2(lo, hi);
    }
  }

  f32x4 acc = {0.f, 0.f, 0.f, 0.f};
  const int cs7 = col & 7;
  const int qh  = q >> 1;
  const int ql8 = (q & 1) * 8;

#define CHUNK(wb, af, n0, n1) { \
    __half2 nv2[8]; \
    nv2[0] = __floats2half2_rn((n0).x, (n0).x); nv2[1] = __floats2half2_rn((n0).y, (n0).y); \
    nv2[2] = __floats2half2_rn((n0).z, (n0).z); nv2[3] = __floats2half2_rn((n0).w, (n0).w); \
    nv2[4] = __floats2half2_rn((n1).x, (n1).x); nv2[5] = __floats2half2_rn((n1).y, (n1).y); \
    nv2[6] = __floats2half2_rn((n1).z, (n1).z); nv2[7] = __floats2half2_rn((n1).w, (n1).w); \
    _Pragma("unroll") \
    for (int j = 0; j < 8; ++j) { \
      const uint2 p  = *(const uint2*)((wb) + col * 256 + (((2 * j + qh) ^ cs7) << 4) + ql8); \
      const uint2 e0 = *(const uint2*)(LUT + ((size_t)(uint)p.x << 3)); \
      const uint2 e1 = *(const uint2*)(LUT + ((size_t)(uint)p.y << 3)); \
      UH a0, a1, a2, a3, b0, b1, b2, b3; \
      a0.u = e0.x; a1.u = e0.y; a2.u = e1.x; a3.u = e1.y; \
      b0.h = __hmul2(a0.h, nv2[j]); b1.h = __hmul2(a1.h, nv2[j]); \
      b2.h = __hmul2(a2.h, nv2[j]); b3.h = __hmul2(a3.h, nv2[j]); \
      UA B; B.u[0] = b0.u; B.u[1] = b1.u; B.u[2] = b2.u; B.u[3] = b3.u; \
      acc = __builtin_amdgcn_mfma_f32_16x16x32_f16((af)[j].v, B.v, acc, 0, 0, 0); \
    } }

  // consume ladder: chunk 0 runs with 2.5 chunks of loads still in flight
  WAITV(24); CHUNK(WB0, afA, nf[0], nf[1])                 // NR+W0+AF0 retired
  FENCE();   STAGE_W(3, WB0);  FENCE();  LOAD_AF(afA, 3);  FENCE();
  WAITV(24); CHUNK(WB1, afB, nf[2], nf[3])                 // W1+AF1 retired
  WAITV(12); CHUNK(WB2, afC, nf[4], nf[5])                 // W2+AF2 retired
  WAITV(0);  CHUNK(WB0, afA, nf[6], nf[7])                 // W3+AF3 retired
#undef CHUNK
#undef STAGE_W
#undef LOAD_AF

  // ---- cross-wave K reduction + bias + store
  __syncthreads();
  float* red = (float*)lds;
  red[wv * 256 +   0 + l] = acc[0];
  red[wv * 256 +  64 + l] = acc[1];
  red[wv * 256 + 128 + l] = acc[2];
  red[wv * 256 + 192 + l] = acc[3];
  __syncthreads();
  const int t = tid;
  const float s = red[t] + red[256 + t] + red[512 + t] + red[768 + t];
  const int m  = ((t & 63) >> 4) * 4 + (t >> 6);
  const int oc = t & 15;
  out[(size_t)m * OUTF + o0 + oc] = s + bias[o0 + oc];
}

extern "C" void kernel_launch(void* const* d_in, const int* in_sizes, int n_in,
                              void* d_out, int out_size, void* d_ws, size_t ws_size,
                              hipStream_t stream) {
  (void)in_sizes; (void)n_in; (void)out_size; (void)ws_size;
  const float* x    = (const float*)d_in[0];
  const int*   wq   = (const int*)d_in[1];
  const float* wn   = (const float*)d_in[2];
  const float* bias = (const float*)d_in[3];
  float*       out  = (float*)d_out;
  uint4*       xpk  = (uint4*)d_ws;   // 128 KB workspace
  pack_x_kernel<<<dim3(32), dim3(256), 0, stream>>>(x, xpk);
  lin2bit_kernel<<<dim3(OUTF / 16), dim3(256), 0, stream>>>(xpk, wq, wn, bias, out);
}